// Round 7
// baseline (141.951 us; speedup 1.0000x reference)
//
#include <hip/hip_runtime.h>
#include <hip/hip_bf16.h>

typedef __attribute__((ext_vector_type(4))) float f32x4;
typedef _Float16 f16;
typedef __attribute__((ext_vector_type(8))) f16 f16x8;
typedef __attribute__((ext_vector_type(4))) f16 f16x4;
typedef __attribute__((ext_vector_type(2))) __fp16 fp16x2;

#define LDQ 136   // 128 cols + 8 pad (16B) -> keeps b128 alignment, spreads banks
#define LDV 72    // 64 cols + 8 pad

// Pack a row-major [K x Ntot] f32 weight into fp16 MFMA B-fragments:
// dst[((nt*4+kst)*64 + lane)*8 + e] = f16(w[32*kst + 8*(lane>>4) + e][16*nt + (lane&15)])
__global__ void pack_w_kernel(const float* __restrict__ w, f16* __restrict__ dst, int Ntot) {
  int idx = blockIdx.x * 256 + threadIdx.x;
  int total = (Ntot / 16) * 4 * 64;
  if (idx >= total) return;
  int lane = idx & 63;
  int kf = (idx >> 6) & 3;
  int nt = idx >> 8;
  int k0 = 32 * kf + 8 * (lane >> 4);
  int n = 16 * nt + (lane & 15);
  f16x8 v;
#pragma unroll
  for (int e = 0; e < 8; e++) v[e] = (f16)w[(k0 + e) * Ntot + n];
  *(f16x8*)(dst + (size_t)idx * 8) = v;
}

// Pre-pack mask into per-lane MFMA C-fragment layout, padding baked in:
// dst[((w*64 + l)*64) + mt*16 + nt*4 + r]
__global__ void pack_mask_kernel(const float* __restrict__ mask, float* __restrict__ dst) {
  int idx = blockIdx.x * 256 + threadIdx.x;  // 64*64*64 = 262144
  int v = idx & 63;
  int l = (idx >> 6) & 63;
  int w = idx >> 12;
  int r = v & 3, nt = (v >> 2) & 3, mt = v >> 4;
  int qr = 16 * mt + 4 * (l >> 4) + r;
  int kc = 16 * nt + (l & 15);
  float val;
  if (kc >= 49) val = -1e30f;
  else if (qr < 49) val = mask[w * 2401 + qr * 49 + kc];
  else val = 0.f;
  dst[idx] = val;
}

__device__ __forceinline__ f16x8 cvt8(const float* p) {
  f32x4 lo = *(const f32x4*)(p);
  f32x4 hi = *(const f32x4*)(p + 4);
  union { f16x8 v; fp16x2 h[4]; } u;
  u.h[0] = __builtin_amdgcn_cvt_pkrtz(lo[0], lo[1]);
  u.h[1] = __builtin_amdgcn_cvt_pkrtz(lo[2], lo[3]);
  u.h[2] = __builtin_amdgcn_cvt_pkrtz(hi[0], hi[1]);
  u.h[3] = __builtin_amdgcn_cvt_pkrtz(hi[2], hi[3]);
  return u.v;
}

// 8 waves per window: wave = (head h, row-half). Each wave owns q-token rows
// [32*half, 32*half+32) of its head. 2 blocks/CU (LDS 106KB), 16 waves/CU.
template <bool PM>
__global__ __launch_bounds__(512, 4) void winattn_main(
    const float* __restrict__ x, const float* __restrict__ mask,
    const float* __restrict__ mask_p,
    const float* __restrict__ bqkv, const float* __restrict__ bproj,
    const f16* __restrict__ wqkv_p, const f16* __restrict__ wproj_p,
    float* __restrict__ out) {
  // Qs doubles as P(lo) and O; Ks doubles as P(hi)
  __shared__ f16 Qs[64 * LDQ];
  __shared__ f16 Ks[64 * LDQ];
  __shared__ f16 Vt[128 * LDV];

  const int tid = threadIdx.x;
  const int wv = tid >> 6;     // wave 0..7
  const int h = wv >> 1;       // head 0..3
  const int half = wv & 1;     // row-half 0..1
  const int l = tid & 63;      // lane
  const int lg = l >> 4;       // lane group 0..3
  const int ll = l & 15;       // lane low
  const int b = blockIdx.x;    // window id
  const int mtb = 2 * half;    // this wave's mt base (mt = mtb, mtb+1)

  const float* xw = x + (size_t)b * 49 * 128;

  // ---------------- stage 1: QKV = x @ Wqkv + b (own head, own row-half) ----------------
  f16x8 af[2][4];
#pragma unroll
  for (int mi = 0; mi < 2; mi++) {
    int row = 16 * (mtb + mi) + ll;
#pragma unroll
    for (int kst = 0; kst < 4; kst++) {
      if (row < 49) {
        af[mi][kst] = cvt8(xw + row * 128 + kst * 32 + 8 * lg);
      } else {
        f16x8 a;
#pragma unroll
        for (int e = 0; e < 8; e++) a[e] = (f16)0.f;
        af[mi][kst] = a;
      }
    }
  }
  // Q tiles: nt = 2h, 2h+1
#pragma unroll
  for (int qi = 0; qi < 2; qi++) {
    int nt = 2 * h + qi;
    f16x8 bfr[4];
#pragma unroll
    for (int kst = 0; kst < 4; kst++)
      bfr[kst] = *(const f16x8*)(wqkv_p + (size_t)(((nt * 4 + kst) * 64) + l) * 8);
    float bias = bqkv[16 * nt + ll];
    int c = 16 * nt + ll;
#pragma unroll
    for (int mi = 0; mi < 2; mi++) {
      f32x4 acc = {0.f, 0.f, 0.f, 0.f};
#pragma unroll
      for (int kst = 0; kst < 4; kst++)
        acc = __builtin_amdgcn_mfma_f32_16x16x32_f16(af[mi][kst], bfr[kst], acc, 0, 0, 0);
#pragma unroll
      for (int r = 0; r < 4; r++)
        Qs[(16 * (mtb + mi) + 4 * lg + r) * LDQ + c] = (f16)(acc[r] + bias);
    }
  }
  // K tiles: nt = 8+2h, 9+2h
#pragma unroll
  for (int ki = 0; ki < 2; ki++) {
    int nt = 8 + 2 * h + ki;
    f16x8 bfr[4];
#pragma unroll
    for (int kst = 0; kst < 4; kst++)
      bfr[kst] = *(const f16x8*)(wqkv_p + (size_t)(((nt * 4 + kst) * 64) + l) * 8);
    float bias = bqkv[16 * nt + ll];
    int c = 32 * h + 16 * ki + ll;
#pragma unroll
    for (int mi = 0; mi < 2; mi++) {
      f32x4 acc = {0.f, 0.f, 0.f, 0.f};
#pragma unroll
      for (int kst = 0; kst < 4; kst++)
        acc = __builtin_amdgcn_mfma_f32_16x16x32_f16(af[mi][kst], bfr[kst], acc, 0, 0, 0);
#pragma unroll
      for (int r = 0; r < 4; r++)
        Ks[(16 * (mtb + mi) + 4 * lg + r) * LDQ + c] = (f16)(acc[r] + bias);
    }
  }
  // V tiles: nt = 16+2h, 17+2h (stored transposed Vt[d_global][token])
#pragma unroll
  for (int vi = 0; vi < 2; vi++) {
    int nt = 16 + 2 * h + vi;
    f16x8 bfr[4];
#pragma unroll
    for (int kst = 0; kst < 4; kst++)
      bfr[kst] = *(const f16x8*)(wqkv_p + (size_t)(((nt * 4 + kst) * 64) + l) * 8);
    float bias = bqkv[16 * nt + ll];
    int c = 32 * h + 16 * vi + ll;  // d_global
#pragma unroll
    for (int mi = 0; mi < 2; mi++) {
      f32x4 acc = {0.f, 0.f, 0.f, 0.f};
#pragma unroll
      for (int kst = 0; kst < 4; kst++)
        acc = __builtin_amdgcn_mfma_f32_16x16x32_f16(af[mi][kst], bfr[kst], acc, 0, 0, 0);
      f16x4 pk;
#pragma unroll
      for (int r = 0; r < 4; r++) pk[r] = (f16)(acc[r] + bias);
      *(f16x4*)(&Vt[c * LDV + 16 * (mtb + mi) + 4 * lg]) = pk;
    }
  }
  __syncthreads();  // K/V tokens cross the half boundary

  // hoist K and V fragments into registers (Vt stable from here on)
  f16x8 kf[4];
#pragma unroll
  for (int nt = 0; nt < 4; nt++)
    kf[nt] = *(const f16x8*)(&Ks[(16 * nt + ll) * LDQ + 32 * h + 8 * lg]);
  f16x8 vf[2][2];
#pragma unroll
  for (int ntd = 0; ntd < 2; ntd++)
#pragma unroll
    for (int kst = 0; kst < 2; kst++)
      vf[ntd][kst] = *(const f16x8*)(&Vt[(32 * h + 16 * ntd + ll) * LDV + 32 * kst + 8 * lg]);
  __syncthreads();  // other half's K fragments read before our P overwrites Ks

  // ---------------- stage 2: S = Q K^T (+mask), softmax (unnormalized P) ----------------
  float inv[2][4];
  const f32x4* mp4 = PM ? (const f32x4*)(mask_p + (((size_t)(b & 63)) * 64 + l) * 64) : nullptr;
  const float* mk = mask + (size_t)(b & 63) * 49 * 49;
#pragma unroll
  for (int mi = 0; mi < 2; mi++) {
    int mt = mtb + mi;
    f32x4 mv[4];
    if (PM) {
#pragma unroll
      for (int nt = 0; nt < 4; nt++) mv[nt] = mp4[mt * 4 + nt];
    }
    f16x8 qf = *(const f16x8*)(&Qs[(16 * mt + ll) * LDQ + 32 * h + 8 * lg]);
    f32x4 s[4];
#pragma unroll
    for (int nt = 0; nt < 4; nt++) {
      f32x4 z = {0.f, 0.f, 0.f, 0.f};
      s[nt] = __builtin_amdgcn_mfma_f32_16x16x32_f16(qf, kf[nt], z, 0, 0, 0);
    }
    if (PM) {
#pragma unroll
      for (int nt = 0; nt < 4; nt++)
#pragma unroll
        for (int r = 0; r < 4; r++) s[nt][r] += mv[nt][r];
    } else {
#pragma unroll
      for (int nt = 0; nt < 4; nt++)
#pragma unroll
        for (int r = 0; r < 4; r++) {
          int qr = 16 * mt + 4 * lg + r;
          int kc = 16 * nt + ll;
          float add;
          if (kc >= 49) add = -1e30f;
          else if (qr < 49) add = mk[qr * 49 + kc];
          else add = 0.f;
          s[nt][r] += add;
        }
    }
#pragma unroll
    for (int r = 0; r < 4; r++) {
      float m = fmaxf(fmaxf(s[0][r], s[1][r]), fmaxf(s[2][r], s[3][r]));
#pragma unroll
      for (int xm = 1; xm < 16; xm <<= 1) m = fmaxf(m, __shfl_xor(m, xm, 64));
      float sum = 0.f;
      f16 pv[4];
#pragma unroll
      for (int nt = 0; nt < 4; nt++) {
        float p = __expf(s[nt][r] - m);
        sum += p;
        pv[nt] = (f16)p;  // unnormalized P
      }
      int q = 16 * mt + 4 * lg + r;
      Qs[q * LDQ + 32 * h + ll] = pv[0];
      Qs[q * LDQ + 32 * h + 16 + ll] = pv[1];
      Ks[q * LDQ + 32 * h + ll] = pv[2];
      Ks[q * LDQ + 32 * h + 16 + ll] = pv[3];
#pragma unroll
      for (int xm = 1; xm < 16; xm <<= 1) sum += __shfl_xor(sum, xm, 64);
      inv[mi][r] = __builtin_amdgcn_rcpf(sum);
    }
  }

  // ---------------- stage 3: O = P @ V, scaled by inv (O back into Qs) ----------------
#pragma unroll
  for (int mi = 0; mi < 2; mi++) {
    int mt = mtb + mi;
    f16x8 a0 = *(const f16x8*)(&Qs[(16 * mt + ll) * LDQ + 32 * h + 8 * lg]);  // keys 0..31
    f16x8 a1 = *(const f16x8*)(&Ks[(16 * mt + ll) * LDQ + 32 * h + 8 * lg]);  // keys 32..63
#pragma unroll
    for (int ntd = 0; ntd < 2; ntd++) {
      f32x4 o = {0.f, 0.f, 0.f, 0.f};
      o = __builtin_amdgcn_mfma_f32_16x16x32_f16(a0, vf[ntd][0], o, 0, 0, 0);
      o = __builtin_amdgcn_mfma_f32_16x16x32_f16(a1, vf[ntd][1], o, 0, 0, 0);
#pragma unroll
      for (int r = 0; r < 4; r++)
        Qs[(16 * mt + 4 * lg + r) * LDQ + 32 * h + 16 * ntd + ll] = (f16)(o[r] * inv[mi][r]);
    }
  }
  __syncthreads();  // stage 4 mixes all heads' O columns

  // ---------------- stage 4: out = O @ Wproj + b (O read from Qs) ----------------
  f16x8 of[2][4];
#pragma unroll
  for (int mi = 0; mi < 2; mi++)
#pragma unroll
    for (int kst = 0; kst < 4; kst++)
      of[mi][kst] = *(const f16x8*)(&Qs[(16 * (mtb + mi) + ll) * LDQ + 32 * kst + 8 * lg]);
#pragma unroll
  for (int nti = 0; nti < 2; nti++) {
    int nt = h + 4 * nti;
    f16x8 bfr[4];
#pragma unroll
    for (int kst = 0; kst < 4; kst++)
      bfr[kst] = *(const f16x8*)(wproj_p + (size_t)(((nt * 4 + kst) * 64) + l) * 8);
    float bias = bproj[16 * nt + ll];
#pragma unroll
    for (int mi = 0; mi < 2; mi++) {
      f32x4 acc = {0.f, 0.f, 0.f, 0.f};
#pragma unroll
      for (int kst = 0; kst < 4; kst++)
        acc = __builtin_amdgcn_mfma_f32_16x16x32_f16(of[mi][kst], bfr[kst], acc, 0, 0, 0);
#pragma unroll
      for (int r = 0; r < 4; r++) {
        int row = 16 * (mtb + mi) + 4 * lg + r;
        if (row < 49)
          out[((size_t)b * 49 + row) * 128 + 16 * nt + ll] = acc[r] + bias;
      }
    }
  }
}

extern "C" void kernel_launch(void* const* d_in, const int* in_sizes, int n_in,
                              void* d_out, int out_size, void* d_ws, size_t ws_size,
                              hipStream_t stream) {
  const float* x = (const float*)d_in[0];
  const float* mask = (const float*)d_in[1];
  const float* wqkv = (const float*)d_in[2];
  const float* bqkv = (const float*)d_in[3];
  const float* wproj = (const float*)d_in[4];
  const float* bproj = (const float*)d_in[5];
  float* out = (float*)d_out;

  f16* wqkv_p = (f16*)d_ws;                   // 24*4*64*8 f16 = 96 KB
  f16* wproj_p = wqkv_p + 24 * 4 * 64 * 8;    // 8*4*64*8 f16 = 32 KB
  float* mask_p = (float*)((char*)d_ws + 128 * 1024);  // 64*64*64 f32 = 1 MB

  const size_t need = 128 * 1024 + 64 * 64 * 64 * sizeof(float);
  const bool pm = ws_size >= need;

  pack_w_kernel<<<24, 256, 0, stream>>>(wqkv, wqkv_p, 384);
  pack_w_kernel<<<8, 256, 0, stream>>>(wproj, wproj_p, 128);
  if (pm) {
    pack_mask_kernel<<<1024, 256, 0, stream>>>(mask, mask_p);
    winattn_main<true><<<4096, 512, 0, stream>>>(x, mask, mask_p, bqkv, bproj, wqkv_p, wproj_p, out);
  } else {
    winattn_main<false><<<4096, 512, 0, stream>>>(x, mask, nullptr, bqkv, bproj, wqkv_p, wproj_p, out);
  }
}

// Round 8
// 136.087 us; speedup vs baseline: 1.0431x; 1.0431x over previous
//
#include <hip/hip_runtime.h>
#include <hip/hip_bf16.h>

typedef __attribute__((ext_vector_type(4))) float f32x4;
typedef _Float16 f16;
typedef __attribute__((ext_vector_type(8))) f16 f16x8;
typedef __attribute__((ext_vector_type(4))) f16 f16x4;
typedef __attribute__((ext_vector_type(2))) __fp16 fp16x2;

#define LDQ 136   // 128 cols + 8 pad
#define LDV 72    // 64 cols + 8 pad

// Pack a row-major [K x Ntot] f32 weight into fp16 MFMA fragments:
// dst[((nt*4+kst)*64 + lane)*8 + e] = f16(w[32*kst + 8*(lane>>4) + e][16*nt + (lane&15)])
// Serves as B-frag (col = 16nt+ll) or A-frag (row = 16nt+ll) interchangeably.
__global__ void pack_w_kernel(const float* __restrict__ w, f16* __restrict__ dst, int Ntot) {
  int idx = blockIdx.x * 256 + threadIdx.x;
  int total = (Ntot / 16) * 4 * 64;
  if (idx >= total) return;
  int lane = idx & 63;
  int kf = (idx >> 6) & 3;
  int nt = idx >> 8;
  int k0 = 32 * kf + 8 * (lane >> 4);
  int n = 16 * nt + (lane & 15);
  f16x8 v;
#pragma unroll
  for (int e = 0; e < 8; e++) v[e] = (f16)w[(k0 + e) * Ntot + n];
  *(f16x8*)(dst + (size_t)idx * 8) = v;
}

// Pre-pack mask TRANSPOSED into per-lane MFMA C-fragment layout for S^T tiles:
// v = nt*16 + mt*4 + r ; q = 16*nt + (l&15), key = 16*mt + 4*(l>>4) + r
// dst[(w*64+l)*64 + v] = key>=49 ? -1e30 : (q<49 ? mask[w][q][key] : 0)
__global__ void pack_mask_kernel(const float* __restrict__ mask, float* __restrict__ dst) {
  int idx = blockIdx.x * 256 + threadIdx.x;  // 64*64*64 = 262144
  int v = idx & 63;
  int l = (idx >> 6) & 63;
  int w = idx >> 12;
  int r = v & 3, mt = (v >> 2) & 3, nt = v >> 4;
  int q = 16 * nt + (l & 15);
  int key = 16 * mt + 4 * (l >> 4) + r;
  float val;
  if (key >= 49) val = -1e30f;
  else if (q < 49) val = mask[w * 2401 + q * 49 + key];
  else val = 0.f;
  dst[idx] = val;
}

__device__ __forceinline__ f16x8 cvt8(const float* p) {
  f32x4 lo = *(const f32x4*)(p);
  f32x4 hi = *(const f32x4*)(p + 4);
  union { f16x8 v; fp16x2 h[4]; } u;
  u.h[0] = __builtin_amdgcn_cvt_pkrtz(lo[0], lo[1]);
  u.h[1] = __builtin_amdgcn_cvt_pkrtz(lo[2], lo[3]);
  u.h[2] = __builtin_amdgcn_cvt_pkrtz(hi[0], hi[1]);
  u.h[3] = __builtin_amdgcn_cvt_pkrtz(hi[2], hi[3]);
  return u.v;
}

__device__ __forceinline__ f16x4 pack4(f32x4 v) {
  union { f16x4 o; fp16x2 h[2]; } u;
  u.h[0] = __builtin_amdgcn_cvt_pkrtz(v[0], v[1]);
  u.h[1] = __builtin_amdgcn_cvt_pkrtz(v[2], v[3]);
  return u.o;
}

template <bool PM>
__global__ __launch_bounds__(256, 3) void winattn_main(
    const float* __restrict__ x, const float* __restrict__ mask,
    const float* __restrict__ mask_p,
    const float* __restrict__ bqkv, const float* __restrict__ bproj,
    const f16* __restrict__ wqkv_p, const f16* __restrict__ wproj_p,
    float* __restrict__ out) {
  // Qs: Q -> P(keys 0..31) -> O ; Ks: K -> P(keys 32..63)
  __shared__ f16 Qs[64 * LDQ];
  __shared__ f16 Ks[64 * LDQ];
  __shared__ f16 Vt[128 * LDV];

  const int tid = threadIdx.x;
  const int h = tid >> 6;    // wave == head
  const int l = tid & 63;
  const int lg = l >> 4;
  const int ll = l & 15;
  const int b = blockIdx.x;

  const float* xw = x + (size_t)b * 49 * 128;

  // ---------------- stage 1: QKV = x @ Wqkv + b ----------------
  // x fragments: token = 16*t + ll, k = 32*kst + 8*lg + e (A- and B-frag compatible)
  f16x8 af[4][4];
#pragma unroll
  for (int t = 0; t < 4; t++) {
    int row = 16 * t + ll;
#pragma unroll
    for (int kst = 0; kst < 4; kst++) {
      if (row < 49) {
        af[t][kst] = cvt8(xw + row * 128 + kst * 32 + 8 * lg);
      } else {
        f16x8 a;
#pragma unroll
        for (int e = 0; e < 8; e++) a[e] = (f16)0.f;
        af[t][kst] = a;
      }
    }
  }
  // Q tiles (swapped: A = W-frag, B = x-frag) -> C: token on ll, feature on (lg,r)
#pragma unroll
  for (int mi = 0; mi < 2; mi++) {
    int ntw = 2 * h + mi;
    f16x8 wf[4];
#pragma unroll
    for (int kst = 0; kst < 4; kst++)
      wf[kst] = *(const f16x8*)(wqkv_p + (size_t)(((ntw * 4 + kst) * 64) + l) * 8);
    f32x4 bq = *(const f32x4*)(bqkv + 16 * ntw + 4 * lg);
#pragma unroll
    for (int t = 0; t < 4; t++) {
      f32x4 acc = {0.f, 0.f, 0.f, 0.f};
#pragma unroll
      for (int kst = 0; kst < 4; kst++)
        acc = __builtin_amdgcn_mfma_f32_16x16x32_f16(wf[kst], af[t][kst], acc, 0, 0, 0);
#pragma unroll
      for (int r = 0; r < 4; r++) acc[r] += bq[r];
      *(f16x4*)(&Qs[(16 * t + ll) * LDQ + 32 * h + 16 * mi + 4 * lg]) = pack4(acc);
    }
  }
  // K tiles (swapped)
#pragma unroll
  for (int mi = 0; mi < 2; mi++) {
    int ntw = 8 + 2 * h + mi;
    f16x8 wf[4];
#pragma unroll
    for (int kst = 0; kst < 4; kst++)
      wf[kst] = *(const f16x8*)(wqkv_p + (size_t)(((ntw * 4 + kst) * 64) + l) * 8);
    f32x4 bk = *(const f32x4*)(bqkv + 16 * ntw + 4 * lg);
#pragma unroll
    for (int t = 0; t < 4; t++) {
      f32x4 acc = {0.f, 0.f, 0.f, 0.f};
#pragma unroll
      for (int kst = 0; kst < 4; kst++)
        acc = __builtin_amdgcn_mfma_f32_16x16x32_f16(wf[kst], af[t][kst], acc, 0, 0, 0);
#pragma unroll
      for (int r = 0; r < 4; r++) acc[r] += bk[r];
      *(f16x4*)(&Ks[(16 * t + ll) * LDQ + 32 * h + 16 * mi + 4 * lg]) = pack4(acc);
    }
  }
  // V tiles (unswapped: A = x-frag, B = W-frag) -> C: d on ll, token on (lg,r); Vt[d][token]
#pragma unroll
  for (int vi = 0; vi < 2; vi++) {
    int ntw = 16 + 2 * h + vi;
    f16x8 wf[4];
#pragma unroll
    for (int kst = 0; kst < 4; kst++)
      wf[kst] = *(const f16x8*)(wqkv_p + (size_t)(((ntw * 4 + kst) * 64) + l) * 8);
    float bv = bqkv[16 * ntw + ll];
    int d = 32 * h + 16 * vi + ll;
#pragma unroll
    for (int t = 0; t < 4; t++) {
      f32x4 acc = {0.f, 0.f, 0.f, 0.f};
#pragma unroll
      for (int kst = 0; kst < 4; kst++)
        acc = __builtin_amdgcn_mfma_f32_16x16x32_f16(af[t][kst], wf[kst], acc, 0, 0, 0);
#pragma unroll
      for (int r = 0; r < 4; r++) acc[r] += bv;
      *(f16x4*)(&Vt[d * LDV + 16 * t + 4 * lg]) = pack4(acc);
    }
  }
  // no barrier: everything below reads only this wave's writes (until stage 4)

  // ---------------- stage 2: S^T = K Q^T (+mask), softmax ----------------
  f16x8 kfA[4], qfB[4];
#pragma unroll
  for (int i = 0; i < 4; i++)
    kfA[i] = *(const f16x8*)(&Ks[(16 * i + ll) * LDQ + 32 * h + 8 * lg]);
#pragma unroll
  for (int i = 0; i < 4; i++)
    qfB[i] = *(const f16x8*)(&Qs[(16 * i + ll) * LDQ + 32 * h + 8 * lg]);

  const f32x4* mp4 = PM ? (const f32x4*)(mask_p + (((size_t)(b & 63)) * 64 + l) * 64) : nullptr;
  const float* mk = mask + (size_t)(b & 63) * 49 * 49;

  f32x4 s[4][4];  // [nt=query tile][mt=key tile]; mask preloaded as C-operand
#pragma unroll
  for (int nt = 0; nt < 4; nt++)
#pragma unroll
    for (int mt = 0; mt < 4; mt++) {
      f32x4 c0;
      if (PM) c0 = mp4[nt * 4 + mt];
      else c0 = (f32x4){0.f, 0.f, 0.f, 0.f};
      s[nt][mt] = __builtin_amdgcn_mfma_f32_16x16x32_f16(kfA[mt], qfB[nt], c0, 0, 0, 0);
    }
  if (!PM) {
#pragma unroll
    for (int nt = 0; nt < 4; nt++)
#pragma unroll
      for (int mt = 0; mt < 4; mt++)
#pragma unroll
        for (int r = 0; r < 4; r++) {
          int q = 16 * nt + ll;
          int key = 16 * mt + 4 * lg + r;
          float add;
          if (key >= 49) add = -1e30f;
          else if (q < 49) add = mk[q * 49 + key];
          else add = 0.f;
          s[nt][mt][r] += add;
        }
  }
  // softmax per query q = 16*nt + ll: 16 in-lane + lanes {ll, ll+16, ll+32, ll+48}
#pragma unroll
  for (int nt = 0; nt < 4; nt++) {
    float m = s[nt][0][0];
#pragma unroll
    for (int mt = 0; mt < 4; mt++)
#pragma unroll
      for (int r = 0; r < 4; r++) m = fmaxf(m, s[nt][mt][r]);
    m = fmaxf(m, __shfl_xor(m, 16));
    m = fmaxf(m, __shfl_xor(m, 32));
    float sum = 0.f;
#pragma unroll
    for (int mt = 0; mt < 4; mt++)
#pragma unroll
      for (int r = 0; r < 4; r++) {
        float p = __expf(s[nt][mt][r] - m);
        s[nt][mt][r] = p;
        sum += p;
      }
    sum += __shfl_xor(sum, 16);
    sum += __shfl_xor(sum, 32);
    float invn = __builtin_amdgcn_rcpf(sum);
    // normalized P -> LDS: keys 0..31 into Qs slice, 32..63 into Ks slice (b64 packed)
#pragma unroll
    for (int mt = 0; mt < 4; mt++) {
      f32x4 pv;
#pragma unroll
      for (int r = 0; r < 4; r++) pv[r] = s[nt][mt][r] * invn;
      if (mt < 2)
        *(f16x4*)(&Qs[(16 * nt + ll) * LDQ + 32 * h + 16 * mt + 4 * lg]) = pack4(pv);
      else
        *(f16x4*)(&Ks[(16 * nt + ll) * LDQ + 32 * h + 16 * (mt - 2) + 4 * lg]) = pack4(pv);
    }
  }

  // ---------------- stage 3: O^T = V^T P^T (swapped) -> O[q][d] b64 packed ----------------
  f16x8 vA[2][2];  // [mi=d tile][kst=key 32-chunk]
#pragma unroll
  for (int mi = 0; mi < 2; mi++)
#pragma unroll
    for (int kst = 0; kst < 2; kst++)
      vA[mi][kst] = *(const f16x8*)(&Vt[(32 * h + 16 * mi + ll) * LDV + 32 * kst + 8 * lg]);
  f16x8 pb0[4], pb1[4];  // P fragments: col q = 16nq+ll, k = key
#pragma unroll
  for (int nq = 0; nq < 4; nq++) {
    pb0[nq] = *(const f16x8*)(&Qs[(16 * nq + ll) * LDQ + 32 * h + 8 * lg]);
    pb1[nq] = *(const f16x8*)(&Ks[(16 * nq + ll) * LDQ + 32 * h + 8 * lg]);
  }
#pragma unroll
  for (int mi = 0; mi < 2; mi++)
#pragma unroll
    for (int nq = 0; nq < 4; nq++) {
      f32x4 o = {0.f, 0.f, 0.f, 0.f};
      o = __builtin_amdgcn_mfma_f32_16x16x32_f16(vA[mi][0], pb0[nq], o, 0, 0, 0);
      o = __builtin_amdgcn_mfma_f32_16x16x32_f16(vA[mi][1], pb1[nq], o, 0, 0, 0);
      // C: col = q = 16nq+ll, row = d-local = 16mi+4lg+r -> O[q][32h+16mi+4lg..+3]
      *(f16x4*)(&Qs[(16 * nq + ll) * LDQ + 32 * h + 16 * mi + 4 * lg]) = pack4(o);
    }

  // hoist stage-4 weight fragments (VMEM hides under barrier)
  f16x8 wf2[2][4];
  f32x4 bp2[2];
#pragma unroll
  for (int moi = 0; moi < 2; moi++) {
    int mo = 2 * h + moi;
#pragma unroll
    for (int kst = 0; kst < 4; kst++)
      wf2[moi][kst] = *(const f16x8*)(wproj_p + (size_t)(((mo * 4 + kst) * 64) + l) * 8);
    bp2[moi] = *(const f32x4*)(bproj + 16 * mo + 4 * lg);
  }
  __syncthreads();  // stage 4 reads all heads' O columns

  // ---------------- stage 4: out^T = Wproj^T O^T (swapped) -> coalesced f32x4 stores ----------------
  f16x8 of[4][4];  // [token tile][kst]: O[16nt+ll][32kst+8lg..]
#pragma unroll
  for (int nt = 0; nt < 4; nt++)
#pragma unroll
    for (int kst = 0; kst < 4; kst++)
      of[nt][kst] = *(const f16x8*)(&Qs[(16 * nt + ll) * LDQ + 32 * kst + 8 * lg]);
#pragma unroll
  for (int moi = 0; moi < 2; moi++) {
    int mo = 2 * h + moi;
#pragma unroll
    for (int nt = 0; nt < 4; nt++) {
      f32x4 acc = {0.f, 0.f, 0.f, 0.f};
#pragma unroll
      for (int kst = 0; kst < 4; kst++)
        acc = __builtin_amdgcn_mfma_f32_16x16x32_f16(wf2[moi][kst], of[nt][kst], acc, 0, 0, 0);
#pragma unroll
      for (int r = 0; r < 4; r++) acc[r] += bp2[moi][r];
      int tok = 16 * nt + ll;
      if (tok < 49)
        *(f32x4*)(&out[((size_t)b * 49 + tok) * 128 + 16 * mo + 4 * lg]) = acc;
    }
  }
}

extern "C" void kernel_launch(void* const* d_in, const int* in_sizes, int n_in,
                              void* d_out, int out_size, void* d_ws, size_t ws_size,
                              hipStream_t stream) {
  const float* x = (const float*)d_in[0];
  const float* mask = (const float*)d_in[1];
  const float* wqkv = (const float*)d_in[2];
  const float* bqkv = (const float*)d_in[3];
  const float* wproj = (const float*)d_in[4];
  const float* bproj = (const float*)d_in[5];
  float* out = (float*)d_out;

  f16* wqkv_p = (f16*)d_ws;                   // 96 KB
  f16* wproj_p = wqkv_p + 24 * 4 * 64 * 8;    // 32 KB
  float* mask_p = (float*)((char*)d_ws + 128 * 1024);  // 1 MB

  const size_t need = 128 * 1024 + 64 * 64 * 64 * sizeof(float);
  const bool pm = ws_size >= need;

  pack_w_kernel<<<24, 256, 0, stream>>>(wqkv, wqkv_p, 384);
  pack_w_kernel<<<8, 256, 0, stream>>>(wproj, wproj_p, 128);
  if (pm) {
    pack_mask_kernel<<<1024, 256, 0, stream>>>(mask, mask_p);
    winattn_main<true><<<4096, 256, 0, stream>>>(x, mask, mask_p, bqkv, bproj, wqkv_p, wproj_p, out);
  } else {
    winattn_main<false><<<4096, 256, 0, stream>>>(x, mask, nullptr, bqkv, bproj, wqkv_p, wproj_p, out);
  }
}

// Round 10
// 120.157 us; speedup vs baseline: 1.1814x; 1.1326x over previous
//
#include <hip/hip_runtime.h>
#include <hip/hip_bf16.h>

typedef __attribute__((ext_vector_type(4))) float f32x4;
typedef _Float16 f16;
typedef __attribute__((ext_vector_type(8))) f16 f16x8;
typedef __attribute__((ext_vector_type(4))) f16 f16x4;
typedef __attribute__((ext_vector_type(2))) __fp16 fp16x2;

#define LDQ 136   // O-buffer row stride (f16): 128 + 8 pad

// Pack a row-major [K x Ntot] f32 weight into fp16 MFMA fragments (K=32 use):
// dst[((nt*4+kst)*64 + lane)*8 + e] = f16(w[32*kst + 8*(lane>>4) + e][16*nt + (lane&15)])
__global__ void pack_w_kernel(const float* __restrict__ w, f16* __restrict__ dst, int Ntot) {
  int idx = blockIdx.x * 256 + threadIdx.x;
  int total = (Ntot / 16) * 4 * 64;
  if (idx >= total) return;
  int lane = idx & 63;
  int kf = (idx >> 6) & 3;
  int nt = idx >> 8;
  int k0 = 32 * kf + 8 * (lane >> 4);
  int n = 16 * nt + (lane & 15);
  f16x8 v;
#pragma unroll
  for (int e = 0; e < 8; e++) v[e] = (f16)w[(k0 + e) * Ntot + n];
  *(f16x8*)(dst + (size_t)idx * 8) = v;
}

// Pre-pack mask TRANSPOSED into per-lane MFMA C-fragment layout for S^T tiles:
// v = nt*16 + mt*4 + r ; q = 16*nt + (l&15), key = 16*mt + 4*(l>>4) + r
__global__ void pack_mask_kernel(const float* __restrict__ mask, float* __restrict__ dst) {
  int idx = blockIdx.x * 256 + threadIdx.x;  // 64*64*64
  int v = idx & 63;
  int l = (idx >> 6) & 63;
  int w = idx >> 12;
  int r = v & 3, mt = (v >> 2) & 3, nt = v >> 4;
  int q = 16 * nt + (l & 15);
  int key = 16 * mt + 4 * (l >> 4) + r;
  float val;
  if (key >= 49) val = -1e30f;
  else if (q < 49) val = mask[w * 2401 + q * 49 + key];
  else val = 0.f;
  dst[idx] = val;
}

__device__ __forceinline__ f16x8 cvt8(const float* p) {
  f32x4 lo = *(const f32x4*)(p);
  f32x4 hi = *(const f32x4*)(p + 4);
  union { f16x8 v; fp16x2 h[4]; } u;
  u.h[0] = __builtin_amdgcn_cvt_pkrtz(lo[0], lo[1]);
  u.h[1] = __builtin_amdgcn_cvt_pkrtz(lo[2], lo[3]);
  u.h[2] = __builtin_amdgcn_cvt_pkrtz(hi[0], hi[1]);
  u.h[3] = __builtin_amdgcn_cvt_pkrtz(hi[2], hi[3]);
  return u.v;
}

__device__ __forceinline__ f16x4 pack4(f32x4 v) {
  union { f16x4 o; fp16x2 h[2]; } u;
  u.h[0] = __builtin_amdgcn_cvt_pkrtz(v[0], v[1]);
  u.h[1] = __builtin_amdgcn_cvt_pkrtz(v[2], v[3]);
  return u.o;
}

// Swapped 16x16 C-tile (col=ll, row=4*lg+r) packed to f16x4 IS the K=16 MFMA
// A/B fragment (idx=lane&15, k=4*(lane>>4)+e) — no cross-lane movement needed.

template <bool PM>
__global__ __launch_bounds__(256, 3) void winattn_main(
    const float* __restrict__ x, const float* __restrict__ mask,
    const float* __restrict__ mask_p,
    const float* __restrict__ bqkv, const float* __restrict__ bproj,
    const f16* __restrict__ wqkv_p, const f16* __restrict__ wproj_p,
    float* __restrict__ out) {
  __shared__ f16 Os[64 * LDQ];  // only O crosses waves

  const int tid = threadIdx.x;
  const int h = tid >> 6;    // wave == head
  const int l = tid & 63;
  const int lg = l >> 4;
  const int ll = l & 15;
  const int b = blockIdx.x;

  const float* xw = x + (size_t)b * 49 * 128;

  // ---------------- stage 1: QKV = x @ Wqkv + b, results stay in registers ----------------
  f16x8 af[4][4];
#pragma unroll
  for (int t = 0; t < 4; t++) {
    int row = 16 * t + ll;
#pragma unroll
    for (int kst = 0; kst < 4; kst++) {
      if (row < 49) {
        af[t][kst] = cvt8(xw + row * 128 + kst * 32 + 8 * lg);
      } else {
        f16x8 a;
#pragma unroll
        for (int e = 0; e < 8; e++) a[e] = (f16)0.f;
        af[t][kst] = a;
      }
    }
  }
  // Q tiles (swapped: C col=token=ll, row=feature 4lg+r) -> f16x4 = stage-2 B-frag chunk
  f16x4 qv[2][4];  // [feature chunk c][token tile t]
#pragma unroll
  for (int mi = 0; mi < 2; mi++) {
    int ntw = 2 * h + mi;
    f16x8 wf[4];
#pragma unroll
    for (int kst = 0; kst < 4; kst++)
      wf[kst] = *(const f16x8*)(wqkv_p + (size_t)(((ntw * 4 + kst) * 64) + l) * 8);
    f32x4 bq = *(const f32x4*)(bqkv + 16 * ntw + 4 * lg);
#pragma unroll
    for (int t = 0; t < 4; t++) {
      f32x4 acc = {0.f, 0.f, 0.f, 0.f};
#pragma unroll
      for (int kst = 0; kst < 4; kst++)
        acc = __builtin_amdgcn_mfma_f32_16x16x32_f16(wf[kst], af[t][kst], acc, 0, 0, 0);
#pragma unroll
      for (int r = 0; r < 4; r++) acc[r] += bq[r];
      qv[mi][t] = pack4(acc);
    }
  }
  // K tiles (swapped) -> stage-2 A-frag chunks
  f16x4 kv[2][4];
#pragma unroll
  for (int mi = 0; mi < 2; mi++) {
    int ntw = 8 + 2 * h + mi;
    f16x8 wf[4];
#pragma unroll
    for (int kst = 0; kst < 4; kst++)
      wf[kst] = *(const f16x8*)(wqkv_p + (size_t)(((ntw * 4 + kst) * 64) + l) * 8);
    f32x4 bk = *(const f32x4*)(bqkv + 16 * ntw + 4 * lg);
#pragma unroll
    for (int t = 0; t < 4; t++) {
      f32x4 acc = {0.f, 0.f, 0.f, 0.f};
#pragma unroll
      for (int kst = 0; kst < 4; kst++)
        acc = __builtin_amdgcn_mfma_f32_16x16x32_f16(wf[kst], af[t][kst], acc, 0, 0, 0);
#pragma unroll
      for (int r = 0; r < 4; r++) acc[r] += bk[r];
      kv[mi][t] = pack4(acc);
    }
  }
  // V tiles (unswapped: C col=d=ll, row=token 4lg+r) -> stage-3 A-frag chunks
  f16x4 vv[2][4];  // [d chunk vi][token tile t]
#pragma unroll
  for (int vi = 0; vi < 2; vi++) {
    int ntw = 16 + 2 * h + vi;
    f16x8 wf[4];
#pragma unroll
    for (int kst = 0; kst < 4; kst++)
      wf[kst] = *(const f16x8*)(wqkv_p + (size_t)(((ntw * 4 + kst) * 64) + l) * 8);
    float bv = bqkv[16 * ntw + ll];
#pragma unroll
    for (int t = 0; t < 4; t++) {
      f32x4 acc = {0.f, 0.f, 0.f, 0.f};
#pragma unroll
      for (int kst = 0; kst < 4; kst++)
        acc = __builtin_amdgcn_mfma_f32_16x16x32_f16(af[t][kst], wf[kst], acc, 0, 0, 0);
#pragma unroll
      for (int r = 0; r < 4; r++) acc[r] += bv;
      vv[vi][t] = pack4(acc);
    }
  }

  // ---------------- stage 2: S^T = K Q^T (K=16 chunks, mask as C-operand), softmax ----------------
  const f32x4* mp4 = PM ? (const f32x4*)(mask_p + (((size_t)(b & 63)) * 64 + l) * 64) : nullptr;
  const float* mk = mask + (size_t)(b & 63) * 49 * 49;
  f16x4 pb[4][4];  // [key tile mt][query tile nt] -> stage-3 B-frag chunks
#pragma unroll
  for (int nt = 0; nt < 4; nt++) {
    f32x4 s[4];
#pragma unroll
    for (int mt = 0; mt < 4; mt++) {
      f32x4 c0;
      if (PM) c0 = mp4[nt * 4 + mt];
      else c0 = (f32x4){0.f, 0.f, 0.f, 0.f};
      c0 = __builtin_amdgcn_mfma_f32_16x16x16f16(kv[0][mt], qv[0][nt], c0, 0, 0, 0);
      s[mt] = __builtin_amdgcn_mfma_f32_16x16x16f16(kv[1][mt], qv[1][nt], c0, 0, 0, 0);
    }
    if (!PM) {
#pragma unroll
      for (int mt = 0; mt < 4; mt++)
#pragma unroll
        for (int r = 0; r < 4; r++) {
          int q = 16 * nt + ll;
          int key = 16 * mt + 4 * lg + r;
          float add;
          if (key >= 49) add = -1e30f;
          else if (q < 49) add = mk[q * 49 + key];
          else add = 0.f;
          s[mt][r] += add;
        }
    }
    // softmax for query q = 16*nt + ll (16 in-lane + lanes ll, ll+16, ll+32, ll+48)
    float m01 = fmaxf(fmaxf(fmaxf(s[0][0], s[0][1]), fmaxf(s[0][2], s[0][3])),
                      fmaxf(fmaxf(s[1][0], s[1][1]), fmaxf(s[1][2], s[1][3])));
    float m23 = fmaxf(fmaxf(fmaxf(s[2][0], s[2][1]), fmaxf(s[2][2], s[2][3])),
                      fmaxf(fmaxf(s[3][0], s[3][1]), fmaxf(s[3][2], s[3][3])));
    float m = fmaxf(m01, m23);
    m = fmaxf(m, __shfl_xor(m, 16));
    m = fmaxf(m, __shfl_xor(m, 32));
#pragma unroll
    for (int mt = 0; mt < 4; mt++)
#pragma unroll
      for (int r = 0; r < 4; r++) s[mt][r] = __expf(s[mt][r] - m);
    float sm0 = (s[0][0] + s[0][1]) + (s[0][2] + s[0][3]);
    float sm1 = (s[1][0] + s[1][1]) + (s[1][2] + s[1][3]);
    float sm2 = (s[2][0] + s[2][1]) + (s[2][2] + s[2][3]);
    float sm3 = (s[3][0] + s[3][1]) + (s[3][2] + s[3][3]);
    float sum = (sm0 + sm1) + (sm2 + sm3);
    sum += __shfl_xor(sum, 16);
    sum += __shfl_xor(sum, 32);
    float invn = __builtin_amdgcn_rcpf(sum);
#pragma unroll
    for (int mt = 0; mt < 4; mt++) {
      f32x4 pv;
#pragma unroll
      for (int r = 0; r < 4; r++) pv[r] = s[mt][r] * invn;
      pb[mt][nt] = pack4(pv);
    }
  }

  // ---------------- stage 3: O^T = V^T P^T (K=16 chunks over key tiles) ----------------
#pragma unroll
  for (int mi = 0; mi < 2; mi++)
#pragma unroll
    for (int nq = 0; nq < 4; nq++) {
      f32x4 o = {0.f, 0.f, 0.f, 0.f};
#pragma unroll
      for (int c = 0; c < 4; c++)
        o = __builtin_amdgcn_mfma_f32_16x16x16f16(vv[mi][c], pb[c][nq], o, 0, 0, 0);
      *(f16x4*)(&Os[(16 * nq + ll) * LDQ + 32 * h + 16 * mi + 4 * lg]) = pack4(o);
    }

  // hoist stage-4 weight fragments (VMEM hides under barrier)
  f16x8 wf2[2][4];
  f32x4 bp2[2];
#pragma unroll
  for (int moi = 0; moi < 2; moi++) {
    int mo = 2 * h + moi;
#pragma unroll
    for (int kst = 0; kst < 4; kst++)
      wf2[moi][kst] = *(const f16x8*)(wproj_p + (size_t)(((mo * 4 + kst) * 64) + l) * 8);
    bp2[moi] = *(const f32x4*)(bproj + 16 * mo + 4 * lg);
  }
  __syncthreads();  // stage 4 reads all heads' O columns

  // ---------------- stage 4: out^T = Wproj^T O^T -> coalesced f32x4 stores ----------------
  f16x8 of[4][4];
#pragma unroll
  for (int nt = 0; nt < 4; nt++)
#pragma unroll
    for (int kst = 0; kst < 4; kst++)
      of[nt][kst] = *(const f16x8*)(&Os[(16 * nt + ll) * LDQ + 32 * kst + 8 * lg]);
#pragma unroll
  for (int moi = 0; moi < 2; moi++) {
    int mo = 2 * h + moi;
#pragma unroll
    for (int nt = 0; nt < 4; nt++) {
      f32x4 acc = {0.f, 0.f, 0.f, 0.f};
#pragma unroll
      for (int kst = 0; kst < 4; kst++)
        acc = __builtin_amdgcn_mfma_f32_16x16x32_f16(wf2[moi][kst], of[nt][kst], acc, 0, 0, 0);
#pragma unroll
      for (int r = 0; r < 4; r++) acc[r] += bp2[moi][r];
      int tok = 16 * nt + ll;
      if (tok < 49)
        *(f32x4*)(&out[((size_t)b * 49 + tok) * 128 + 16 * mo + 4 * lg]) = acc;
    }
  }
}

extern "C" void kernel_launch(void* const* d_in, const int* in_sizes, int n_in,
                              void* d_out, int out_size, void* d_ws, size_t ws_size,
                              hipStream_t stream) {
  const float* x = (const float*)d_in[0];
  const float* mask = (const float*)d_in[1];
  const float* wqkv = (const float*)d_in[2];
  const float* bqkv = (const float*)d_in[3];
  const float* wproj = (const float*)d_in[4];
  const float* bproj = (const float*)d_in[5];
  float* out = (float*)d_out;

  f16* wqkv_p = (f16*)d_ws;                   // 96 KB
  f16* wproj_p = wqkv_p + 24 * 4 * 64 * 8;    // 32 KB
  float* mask_p = (float*)((char*)d_ws + 128 * 1024);  // 1 MB

  const size_t need = 128 * 1024 + 64 * 64 * 64 * sizeof(float);
  const bool pm = ws_size >= need;

  pack_w_kernel<<<24, 256, 0, stream>>>(wqkv, wqkv_p, 384);
  pack_w_kernel<<<8, 256, 0, stream>>>(wproj, wproj_p, 128);
  if (pm) {
    pack_mask_kernel<<<1024, 256, 0, stream>>>(mask, mask_p);
    winattn_main<true><<<4096, 256, 0, stream>>>(x, mask, mask_p, bqkv, bproj, wqkv_p, wproj_p, out);
  } else {
    winattn_main<false><<<4096, 256, 0, stream>>>(x, mask, nullptr, bqkv, bproj, wqkv_p, wproj_p, out);
  }
}